// Round 1
// baseline (699.573 us; speedup 1.0000x reference)
//
#include <hip/hip_runtime.h>

// Problem constants
#define C_DIM 512
#define V_DIM 1024

typedef __attribute__((ext_vector_type(8))) short short8;   // 8 bf16 (4 VGPRs)
typedef __attribute__((ext_vector_type(4))) float f32x4;

__device__ __forceinline__ short f2bf(float f) {
  unsigned int u = __float_as_uint(f);
  u += 0x7fffu + ((u >> 16) & 1u);           // RNE
  return (short)(u >> 16);
}

__device__ __forceinline__ float fast_tanh_f(float x) {
  // tanh(x) = 1 - 2/(exp(2x)+1); saturates correctly at +/-inf
  float e = __expf(2.0f * x);
  return fmaf(-2.0f, __builtin_amdgcn_rcpf(e + 1.0f), 1.0f);
}

// ---------------------------------------------------------------------------
// Kernel 1 (unchanged, proven): cast W (V,C) fp32 -> bf16, swizzled so that a
// B fragment read for (vt,kc,col,qd) is one contiguous 16 B:
//   wsw + (vt*16+kc)*16384 + vloc*64 + q*16, elements c = kc*32 + q*8 + j.
// ---------------------------------------------------------------------------
__global__ __launch_bounds__(256) void wswz_kernel(const float* __restrict__ W,
                                                   char* __restrict__ wsw) {
  const int i = blockIdx.x * 256 + threadIdx.x;   // 65536 threads
  const int v = i >> 6;
  const int c0 = (i & 63) << 3;
  const float* wp = W + (size_t)v * C_DIM + c0;
  const f32x4 w0 = *(const f32x4*)(wp);
  const f32x4 w1 = *(const f32x4*)(wp + 4);
  short8 pk;
  pk[0] = f2bf(w0[0]); pk[1] = f2bf(w0[1]); pk[2] = f2bf(w0[2]); pk[3] = f2bf(w0[3]);
  pk[4] = f2bf(w1[0]); pk[5] = f2bf(w1[1]); pk[6] = f2bf(w1[2]); pk[7] = f2bf(w1[3]);
  const int vt = v >> 8, vloc = v & 255;
  const int kc = c0 >> 5, q = (c0 >> 3) & 3;
  char* dst = wsw + (size_t)(vt * 16 + kc) * 16384 + vloc * 64 + q * 16;
  *(short8*)dst = pk;
}

// ---------------------------------------------------------------------------
// Kernel 2 (redesigned): K-chunked fused joiner.
//   grid = 8192 blocks = 2048 row-panels (64 rows) x 4 v-tiles (256 cols)
//   block = 256 thr = 4 waves (1 x 4), wave tile 64x64, 16x16x32 bf16 MFMA
//   A: tanh(enc+pred) staged per K-chunk (64x32 bf16 = 4 KB) into 2x4 KB LDS
//   B: fragments loaded global->reg from L2-resident swizzled W, 1 chunk ahead
//   LDS = 8 KB, VGPR-capped for 3 blocks/CU => barrier/store/VALU overlap.
// ---------------------------------------------------------------------------
__global__ __launch_bounds__(256, 3) void joiner_kernel(
    const float* __restrict__ enc, const float* __restrict__ pred,
    const char* __restrict__ wsw, const float* __restrict__ bias,
    float* __restrict__ out) {
  __shared__ char abuf[2][4096];
  const int tid = threadIdx.x;
  const int lane = tid & 63;
  const int wn = tid >> 6;                 // wave 0..3 = column block
  const int l15 = lane & 15, qd = lane >> 4;

  // Bijective XCD swizzle (8192 % 8 == 0): each XCD gets 1024 consecutive
  // work ids -> row-panel locality (enc/pred/out) within an XCD's L2.
  const int bid = blockIdx.x;
  const int wk = ((bid & 7) << 10) | (bid >> 3);
  const int rp = wk >> 2;                  // row panel 0..2047 (64 rows each)
  const int vt = wk & 3;                   // v-tile 0..3
  const int n = rp >> 8;                   // batch; note n*256 + t == rp

  // ---- A staging addresses: thread -> (row si = u, quad sq), k = kc*32+sq*8+j
  const float* pe = enc + (size_t)rp * C_DIM + (tid & 3) * 8;            // enc row (broadcast over u)
  const float* pp = pred + ((size_t)(n << 6) + (tid >> 2)) * C_DIM + (tid & 3) * 8;
  char* adst = &abuf[0][0] + tid * 16;     // linear ds_write_b128, conflict-free

  // ---- B fragment base: (vt, wn, l15, qd); per (kc,nt) add kc*16384 + nt*1024
  const char* wbase = wsw + (size_t)vt * (16 * 16384) + (size_t)(wn * 64 + l15) * 64 + qd * 16;

  // ---- A fragment base: row = mt*16 + l15, k-seg qd (contiguous 1 KB per mt)
  const char* afr = &abuf[0][0] + l15 * 64 + qd * 16;

  f32x4 acc[4][4];
#pragma unroll
  for (int mt = 0; mt < 4; ++mt)
#pragma unroll
    for (int nt = 0; nt < 4; ++nt) acc[mt][nt] = (f32x4){0.f, 0.f, 0.f, 0.f};

  short8 bfr[2][4];                        // B ping-pong (static-indexed via unroll)

  // ---- prologue: stage A chunk 0, issue B frags chunk 0
  {
    const f32x4 e0 = *(const f32x4*)(pe);
    const f32x4 e1 = *(const f32x4*)(pe + 4);
    const f32x4 p0 = *(const f32x4*)(pp);
    const f32x4 p1 = *(const f32x4*)(pp + 4);
    short8 pk;
    pk[0] = f2bf(fast_tanh_f(e0[0] + p0[0]));
    pk[1] = f2bf(fast_tanh_f(e0[1] + p0[1]));
    pk[2] = f2bf(fast_tanh_f(e0[2] + p0[2]));
    pk[3] = f2bf(fast_tanh_f(e0[3] + p0[3]));
    pk[4] = f2bf(fast_tanh_f(e1[0] + p1[0]));
    pk[5] = f2bf(fast_tanh_f(e1[1] + p1[1]));
    pk[6] = f2bf(fast_tanh_f(e1[2] + p1[2]));
    pk[7] = f2bf(fast_tanh_f(e1[3] + p1[3]));
    *(short8*)(adst) = pk;
  }
#pragma unroll
  for (int nt = 0; nt < 4; ++nt)
    bfr[0][nt] = *(const short8*)(wbase + nt * 1024);
  __syncthreads();

#pragma unroll 2
  for (int kc = 0; kc < 16; ++kc) {
    const int cb = kc & 1, nb = cb ^ 1;    // static after unroll-2 (rule #20)

    // Issue next-chunk inputs EARLY (consumed after the MFMA block): e/p for
    // A(kc+1) and B frags (kc+1). ~300 cyc of L2 latency hides under 16 MFMAs.
    f32x4 e0, e1, p0, p1;
    if (kc < 15) {
      const float* pe1 = pe + (kc + 1) * 32;
      const float* pp1 = pp + (kc + 1) * 32;
      e0 = *(const f32x4*)(pe1);
      e1 = *(const f32x4*)(pe1 + 4);
      p0 = *(const f32x4*)(pp1);
      p1 = *(const f32x4*)(pp1 + 4);
#pragma unroll
      for (int nt = 0; nt < 4; ++nt)
        bfr[nb][nt] = *(const short8*)(wbase + (kc + 1) * 16384 + nt * 1024);
    }

    // A fragments for chunk kc (contiguous 1024 B per read across the wave)
    const char* ab = afr + cb * 4096;
    const short8 a0 = *(const short8*)(ab);
    const short8 a1 = *(const short8*)(ab + 1024);
    const short8 a2 = *(const short8*)(ab + 2048);
    const short8 a3 = *(const short8*)(ab + 3072);

    acc[0][0] = __builtin_amdgcn_mfma_f32_16x16x32_bf16(a0, bfr[cb][0], acc[0][0], 0, 0, 0);
    acc[0][1] = __builtin_amdgcn_mfma_f32_16x16x32_bf16(a0, bfr[cb][1], acc[0][1], 0, 0, 0);
    acc[0][2] = __builtin_amdgcn_mfma_f32_16x16x32_bf16(a0, bfr[cb][2], acc[0][2], 0, 0, 0);
    acc[0][3] = __builtin_amdgcn_mfma_f32_16x16x32_bf16(a0, bfr[cb][3], acc[0][3], 0, 0, 0);
    acc[1][0] = __builtin_amdgcn_mfma_f32_16x16x32_bf16(a1, bfr[cb][0], acc[1][0], 0, 0, 0);
    acc[1][1] = __builtin_amdgcn_mfma_f32_16x16x32_bf16(a1, bfr[cb][1], acc[1][1], 0, 0, 0);
    acc[1][2] = __builtin_amdgcn_mfma_f32_16x16x32_bf16(a1, bfr[cb][2], acc[1][2], 0, 0, 0);
    acc[1][3] = __builtin_amdgcn_mfma_f32_16x16x32_bf16(a1, bfr[cb][3], acc[1][3], 0, 0, 0);
    acc[2][0] = __builtin_amdgcn_mfma_f32_16x16x32_bf16(a2, bfr[cb][0], acc[2][0], 0, 0, 0);
    acc[2][1] = __builtin_amdgcn_mfma_f32_16x16x32_bf16(a2, bfr[cb][1], acc[2][1], 0, 0, 0);
    acc[2][2] = __builtin_amdgcn_mfma_f32_16x16x32_bf16(a2, bfr[cb][2], acc[2][2], 0, 0, 0);
    acc[2][3] = __builtin_amdgcn_mfma_f32_16x16x32_bf16(a2, bfr[cb][3], acc[2][3], 0, 0, 0);
    acc[3][0] = __builtin_amdgcn_mfma_f32_16x16x32_bf16(a3, bfr[cb][0], acc[3][0], 0, 0, 0);
    acc[3][1] = __builtin_amdgcn_mfma_f32_16x16x32_bf16(a3, bfr[cb][1], acc[3][1], 0, 0, 0);
    acc[3][2] = __builtin_amdgcn_mfma_f32_16x16x32_bf16(a3, bfr[cb][2], acc[3][2], 0, 0, 0);
    acc[3][3] = __builtin_amdgcn_mfma_f32_16x16x32_bf16(a3, bfr[cb][3], acc[3][3], 0, 0, 0);

    // Stage A chunk kc+1. Safe: abuf[nb] was last read in iter kc-1, and the
    // barrier at end of kc-1 ordered those reads before these writes.
    if (kc < 15) {
      short8 pk;
      pk[0] = f2bf(fast_tanh_f(e0[0] + p0[0]));
      pk[1] = f2bf(fast_tanh_f(e0[1] + p0[1]));
      pk[2] = f2bf(fast_tanh_f(e0[2] + p0[2]));
      pk[3] = f2bf(fast_tanh_f(e0[3] + p0[3]));
      pk[4] = f2bf(fast_tanh_f(e1[0] + p1[0]));
      pk[5] = f2bf(fast_tanh_f(e1[1] + p1[1]));
      pk[6] = f2bf(fast_tanh_f(e1[2] + p1[2]));
      pk[7] = f2bf(fast_tanh_f(e1[3] + p1[3]));
      *(short8*)(adst + nb * 4096) = pk;
    }
    __syncthreads();                       // drains lgkm: abuf[nb] ready for kc+1
  }

  // ---- epilogue (once per block, overlapped across 3 resident blocks)
  // C/D layout: col = lane&15, row = (lane>>4)*4 + reg  [m89/m91, proven]
  const int colb = (vt << 8) + (wn << 6) + l15;
  const size_t r0 = ((size_t)rp << 6) + (qd << 2);
#pragma unroll
  for (int nt = 0; nt < 4; ++nt) {
    const float bb = bias[colb + nt * 16];
#pragma unroll
    for (int mt = 0; mt < 4; ++mt) {
      float* op = out + (r0 + mt * 16) * V_DIM + colb + nt * 16;
      op[0 * V_DIM] = acc[mt][nt][0] + bb;
      op[1 * V_DIM] = acc[mt][nt][1] + bb;
      op[2 * V_DIM] = acc[mt][nt][2] + bb;
      op[3 * V_DIM] = acc[mt][nt][3] + bb;
    }
  }
}

extern "C" void kernel_launch(void* const* d_in, const int* in_sizes, int n_in,
                              void* d_out, int out_size, void* d_ws, size_t ws_size,
                              hipStream_t stream) {
  const float* enc  = (const float*)d_in[0];   // (8,256,512)
  const float* pred = (const float*)d_in[1];   // (8,64,512)
  const float* W    = (const float*)d_in[2];   // (1024,512)
  const float* bias = (const float*)d_in[3];   // (1024,)
  float* out = (float*)d_out;                  // (8,256,64,1024)
  char* wsw = (char*)d_ws;                     // 1 MB swizzled bf16 W

  wswz_kernel<<<dim3(256), dim3(256), 0, stream>>>(W, wsw);
  joiner_kernel<<<dim3(8192), dim3(256), 0, stream>>>(enc, pred, wsw, bias, out);
}

// Round 2
// 629.008 us; speedup vs baseline: 1.1122x; 1.1122x over previous
//
#include <hip/hip_runtime.h>

// Problem constants
#define C_DIM 512
#define V_DIM 1024

typedef __attribute__((ext_vector_type(8))) short short8;    // 8 bf16 (4 VGPRs)
typedef __attribute__((ext_vector_type(4))) float f32x4;
typedef __attribute__((ext_vector_type(16))) float f32x16;   // 32x32 MFMA acc

__device__ __forceinline__ short f2bf(float f) {
  unsigned int u = __float_as_uint(f);
  u += 0x7fffu + ((u >> 16) & 1u);           // RNE
  return (short)(u >> 16);
}

__device__ __forceinline__ float fast_tanh_f(float x) {
  // tanh(x) = 1 - 2/(exp(2x)+1); saturates correctly at +/-inf
  float e = __expf(2.0f * x);
  return fmaf(-2.0f, __builtin_amdgcn_rcpf(e + 1.0f), 1.0f);
}

// ---------------------------------------------------------------------------
// Kernel 1: cast W (V,C) fp32 -> bf16 into the 32x32-MFMA B-fragment image:
//   chunk (vt,kc) = 16 KB; inside: [wn(4)][nt(2)][s(2)][hi(2)][c32(32)] x 16B
//   element (v,c): v = vt*256 + wn*64 + nt*32 + c32
//                  c = kc*32 + s*16 + hi*8 + j   (j = 0..7 inside the 16B)
// A wave's fragment read (wn,nt,s) is then contiguous 1024 B (lane = hi*32+c32).
// ---------------------------------------------------------------------------
__global__ __launch_bounds__(256) void wswz_kernel(const float* __restrict__ W,
                                                   char* __restrict__ wsw) {
  const int i = blockIdx.x * 256 + threadIdx.x;   // 65536 threads
  const int v = i >> 6;
  const int c0 = (i & 63) << 3;
  const float* wp = W + (size_t)v * C_DIM + c0;
  const f32x4 w0 = *(const f32x4*)(wp);
  const f32x4 w1 = *(const f32x4*)(wp + 4);
  short8 pk;
  pk[0] = f2bf(w0[0]); pk[1] = f2bf(w0[1]); pk[2] = f2bf(w0[2]); pk[3] = f2bf(w0[3]);
  pk[4] = f2bf(w1[0]); pk[5] = f2bf(w1[1]); pk[6] = f2bf(w1[2]); pk[7] = f2bf(w1[3]);
  const int vt = v >> 8, vloc = v & 255;
  const int wn = vloc >> 6, nt = (vloc >> 5) & 1, c32 = vloc & 31;
  const int kc = c0 >> 5, s = (c0 >> 4) & 1, hi = (c0 >> 3) & 1;
  char* dst = wsw + (size_t)(vt * 16 + kc) * 16384 +
              wn * 4096 + nt * 2048 + s * 1024 + hi * 512 + c32 * 16;
  *(short8*)dst = pk;
}

// ---------------------------------------------------------------------------
// Kernel 2: persistent-A joiner.
//   grid = 2048 blocks (one 64-row panel each), block = 256 thr = 4 waves.
//   Block output: 64 rows x 1024 cols (4 v-tiles iterated with the SAME A).
//   Phase 1: tanh(enc+pred) -> bf16 A image [kc(16)][mt(2)][s(2)][hi(2)][r(32)]
//            in 64 KB LDS; ONE __syncthreads.
//   Phase 2: barrier-free 64-iter loop: 8x mfma_32x32x16 per iter, wave tile
//            64x64 (2mt x 2nt), B global->reg from L2-resident wsw (ping-pong
//            prefetch), A ds_read prefetch. Nontemporal epilogue per v-tile.
//   LDS 64 KB -> 2 blocks/CU; VGPR ~150 -> no spill, waves self-stagger.
// ---------------------------------------------------------------------------
__global__ __launch_bounds__(256, 2) void joiner_kernel(
    const float* __restrict__ enc, const float* __restrict__ pred,
    const char* __restrict__ wsw, const float* __restrict__ bias,
    float* __restrict__ out) {
  extern __shared__ char smem[];          // 65536 B A image
  const int tid = threadIdx.x;
  const int lane = tid & 63;
  const int wn = tid >> 6;                // wave 0..3 = 64-col block
  const int l31 = lane & 31, hf = lane >> 5;

  // Bijective XCD swizzle (2048 % 8 == 0): 256 consecutive panels per XCD.
  const int bid = blockIdx.x;
  const int rp = ((bid & 7) << 8) | (bid >> 3);   // row panel 0..2047
  const int n = rp >> 8;                  // batch (rp = n*256 + t)

  // ---- Phase 1: stage A = tanh(enc+pred) for all K (64 rows x 512 k, bf16)
  {
    const int mt_s = tid >> 7;                    // row-half (u block)
    const int rr = tid & 31;
    const int u = mt_s * 32 + rr;
    const int koff = ((tid >> 6) & 1) * 16 + ((tid >> 5) & 1) * 8;
    const float* pe = enc + (size_t)rp * C_DIM + koff;
    const float* pp = pred + ((size_t)(n * 64 + u)) * C_DIM + koff;
    char* adst = smem + tid * 16;                 // linear ds_write_b128
#pragma unroll 4
    for (int kc = 0; kc < 16; ++kc) {
      const f32x4 e0 = *(const f32x4*)(pe + kc * 32);
      const f32x4 e1 = *(const f32x4*)(pe + kc * 32 + 4);
      const f32x4 p0 = *(const f32x4*)(pp + kc * 32);
      const f32x4 p1 = *(const f32x4*)(pp + kc * 32 + 4);
      short8 pk;
      pk[0] = f2bf(fast_tanh_f(e0[0] + p0[0]));
      pk[1] = f2bf(fast_tanh_f(e0[1] + p0[1]));
      pk[2] = f2bf(fast_tanh_f(e0[2] + p0[2]));
      pk[3] = f2bf(fast_tanh_f(e0[3] + p0[3]));
      pk[4] = f2bf(fast_tanh_f(e1[0] + p1[0]));
      pk[5] = f2bf(fast_tanh_f(e1[1] + p1[1]));
      pk[6] = f2bf(fast_tanh_f(e1[2] + p1[2]));
      pk[7] = f2bf(fast_tanh_f(e1[3] + p1[3]));
      *(short8*)(adst + kc * 4096) = pk;
    }
  }
  __syncthreads();                        // the ONLY barrier

  // ---- fragment bases
  // A frag (kc,mt,s): smem + kc*4096 + (mt*2+s)*1024 + hf*512 + l31*16
  const char* ab = smem + hf * 512 + l31 * 16;
  // B frag (g,nt,s): wsw + g*16384 + wn*4096 + (nt*2+s)*1024 + hf*512 + l31*16
  const char* wb = wsw + wn * 4096 + hf * 512 + l31 * 16;

  f32x16 acc[2][2];
#pragma unroll
  for (int mt = 0; mt < 2; ++mt)
#pragma unroll
    for (int nt = 0; nt < 2; ++nt)
#pragma unroll
      for (int r = 0; r < 16; ++r) acc[mt][nt][r] = 0.0f;

  short8 afr[2][4], bfr[2][4];            // ping-pong, frag id = {mt|nt}*2+s

  // ---- prologue: fragments for g = 0 (vt=0, kc=0)
#pragma unroll
  for (int f = 0; f < 4; ++f) {
    bfr[0][f] = *(const short8*)(wb + f * 1024);
    afr[0][f] = *(const short8*)(ab + f * 1024);
  }

  for (int vt = 0; vt < 4; ++vt) {
    const char* wg = wb + (size_t)vt * 262144;    // this v-tile's 16 chunks
#pragma unroll
    for (int kc = 0; kc < 16; ++kc) {
      const int cb = kc & 1, nb = cb ^ 1;         // g parity == kc parity

      // prefetch fragments for g+1 (B crosses v-tile boundary linearly)
      if (kc < 15 || vt < 3) {
        const char* bp = wg + (kc + 1) * 16384;
        const char* ap = ab + ((kc + 1) & 15) * 4096;
#pragma unroll
        for (int f = 0; f < 4; ++f) {
          bfr[nb][f] = *(const short8*)(bp + f * 1024);
          afr[nb][f] = *(const short8*)(ap + f * 1024);
        }
      }

      __builtin_amdgcn_s_setprio(1);
#pragma unroll
      for (int s = 0; s < 2; ++s)
#pragma unroll
        for (int mt = 0; mt < 2; ++mt)
#pragma unroll
          for (int nt = 0; nt < 2; ++nt)
            acc[mt][nt] = __builtin_amdgcn_mfma_f32_32x32x16_bf16(
                afr[cb][mt * 2 + s], bfr[cb][nt * 2 + s], acc[mt][nt], 0, 0, 0);
      __builtin_amdgcn_s_setprio(0);
    }

    // ---- epilogue for this v-tile (no barrier; overlaps other waves/blocks)
    // C/D layout (m74/m101): col = lane&31, row = (reg&3) + 8*(reg>>2) + 4*hf
    {
      const int colb = (vt << 8) + (wn << 6) + l31;
      float* ob = out + ((size_t)rp * 64 + hf * 4) * V_DIM + colb;
#pragma unroll
      for (int nt = 0; nt < 2; ++nt) {
        const float bb = bias[colb + nt * 32];
#pragma unroll
        for (int mt = 0; mt < 2; ++mt) {
#pragma unroll
          for (int r = 0; r < 16; ++r) {
            const int row_off = mt * 32 + (r & 3) + 8 * (r >> 2);
            __builtin_nontemporal_store(acc[mt][nt][r] + bb,
                                        ob + (size_t)row_off * V_DIM + nt * 32);
            acc[mt][nt][r] = 0.0f;        // reset for next v-tile
          }
        }
      }
    }
  }
}

extern "C" void kernel_launch(void* const* d_in, const int* in_sizes, int n_in,
                              void* d_out, int out_size, void* d_ws, size_t ws_size,
                              hipStream_t stream) {
  const float* enc  = (const float*)d_in[0];   // (8,256,512)
  const float* pred = (const float*)d_in[1];   // (8,64,512)
  const float* W    = (const float*)d_in[2];   // (1024,512)
  const float* bias = (const float*)d_in[3];   // (1024,)
  float* out = (float*)d_out;                  // (8,256,64,1024)
  char* wsw = (char*)d_ws;                     // 1 MB swizzled bf16 W

  wswz_kernel<<<dim3(256), dim3(256), 0, stream>>>(W, wsw);

  (void)hipFuncSetAttribute((const void*)joiner_kernel,
                            hipFuncAttributeMaxDynamicSharedMemorySize, 65536);
  joiner_kernel<<<dim3(2048), dim3(256), 65536, stream>>>(enc, pred, wsw, bias, out);
}